// Round 6
// baseline (481.735 us; speedup 1.0000x reference)
//
#include <hip/hip_runtime.h>

#define N_NODES 10000
#define N_EDGES 160000
#define MAXT     22000   // >= sum(max(1,ceil(deg/16)))
#define MSG_BLOCKS 4096  // x4 waves = 16384 waves; /8 groups = 2048 tile-stride

typedef __attribute__((ext_vector_type(8))) __bf16 bf16x8;
typedef __attribute__((ext_vector_type(8))) unsigned short u16x8;
typedef __attribute__((ext_vector_type(4))) float f32x4;

static __device__ __forceinline__ unsigned short f2bf(float x) {
    union { float f; unsigned u; } un;
    un.f = x;
    unsigned r = un.u + 0x7fffu + ((un.u >> 16) & 1u);  // RNE
    return (unsigned short)(r >> 16);
}

static __device__ __forceinline__ float bf2f(unsigned short h) {
    union { unsigned u; float f; } un;
    un.u = ((unsigned)h) << 16;
    return un.f;
}

// ---------------------------------------------------------------------------
// weights: W->bf16 transposes, vbf2 pack, degree histogram. 1.28M threads.
// ---------------------------------------------------------------------------
__global__ __launch_bounds__(256) void weights_kernel(
    const float* __restrict__ v, const int* __restrict__ eix,
    const float* __restrict__ W1, const float* __restrict__ W2,
    const float* __restrict__ Wr,
    unsigned short* __restrict__ vbf2, int* __restrict__ cnt,
    unsigned short* __restrict__ W1T, unsigned short* __restrict__ W2T,
    unsigned short* __restrict__ WrT)
{
    int tid = blockIdx.x * 256 + threadIdx.x;
    if (tid < N_NODES * 128) {
        int n = tid >> 7, f = tid & 127;
        ushort4 q;
        q.x = f2bf(v[(size_t)n * 384 + f]);
        q.y = f2bf(v[(size_t)n * 384 + 128 + f]);
        q.z = f2bf(v[(size_t)n * 384 + 256 + f]);
        q.w = 0;
        *reinterpret_cast<ushort4*>(vbf2 + (size_t)tid * 4) = q;
    }
    if (tid < 131072) {                          // W2T [1024][128]
        int n = tid >> 7, k = tid & 127;
        W2T[tid] = f2bf(W2[k * 1024 + n]);
    }
    if (tid < 16384) {                           // W1T [128][128]
        int n = tid >> 7, k = tid & 127;
        W1T[tid] = f2bf(W1[k * 128 + n]);
    }
    if (tid < 32768) {                           // WrT [1024][32]
        int n = tid >> 5, k = tid & 31;
        WrT[tid] = f2bf(Wr[k * 1024 + n]);
    }
    if (tid < N_EDGES) atomicAdd(&cnt[eix[tid]], 1);
}

// ---------------------------------------------------------------------------
// Single-pass dual scan + tile emission (2 barriers). Out-of-range slots
// contribute 0 tiles (R4 crash fix); deg-0 in-range nodes get 1 empty tile.
// ---------------------------------------------------------------------------
#define NPT 10
__global__ __launch_bounds__(1024) void scan_kernel(
    const int* __restrict__ cnt, int* __restrict__ cursor,
    int* __restrict__ tile_node, int* __restrict__ tile_e0,
    int* __restrict__ tile_cnt, int* __restrict__ ntiles)
{
    __shared__ int ws0[16], ws1[16];
    int t = threadIdx.x, lane = t & 63, wid = t >> 6;
    int n0 = t * NPT;
    int deg[NPT], tc[NPT];
    int D = 0, T = 0;
    #pragma unroll
    for (int i = 0; i < NPT; ++i) {
        int idx = n0 + i;
        int d = (idx < N_NODES) ? cnt[idx] : 0;
        deg[i] = d;
        tc[i] = (idx < N_NODES) ? (d ? ((d + 15) >> 4) : 1) : 0;
        D += d; T += tc[i];
    }
    int x0 = D, x1 = T;
    #pragma unroll
    for (int o = 1; o < 64; o <<= 1) {
        int y0 = __shfl_up(x0, o), y1 = __shfl_up(x1, o);
        if (lane >= o) { x0 += y0; x1 += y1; }
    }
    if (lane == 63) { ws0[wid] = x0; ws1[wid] = x1; }
    __syncthreads();
    if (wid == 0) {
        int w0 = (lane < 16) ? ws0[lane] : 0;
        int w1 = (lane < 16) ? ws1[lane] : 0;
        #pragma unroll
        for (int o = 1; o < 16; o <<= 1) {
            int y0 = __shfl_up(w0, o), y1 = __shfl_up(w1, o);
            if (lane >= o) { w0 += y0; w1 += y1; }
        }
        if (lane < 16) { ws0[lane] = w0; ws1[lane] = w1; }
    }
    __syncthreads();
    int e0 = (wid ? ws0[wid - 1] : 0) + x0 - D;
    int t0 = (wid ? ws1[wid - 1] : 0) + x1 - T;
    #pragma unroll
    for (int i = 0; i < NPT; ++i) {
        int idx = n0 + i;
        if (idx < N_NODES) {
            cursor[idx] = e0;
            for (int k = 0; k < tc[i]; ++k) {
                tile_node[t0 + k] = (idx << 1) | (k == 0);
                tile_e0[t0 + k]   = e0 + k * 16;
                int rem = deg[i] - k * 16;
                tile_cnt[t0 + k]  = rem < 0 ? 0 : (rem < 16 ? rem : 16);
            }
            e0 += deg[i]; t0 += tc[i];
        }
    }
    if (t == 1023) *ntiles = t0;
}

// ---------------------------------------------------------------------------
// rc: Rc = R1*f1 + R2*f2 + R3*f3 (bf16, edge order), fsum, CSR fill.
// ---------------------------------------------------------------------------
__global__ __launch_bounds__(256) void rc_kernel(
    const float* __restrict__ R1, const float* __restrict__ R2,
    const float* __restrict__ R3,
    const float* __restrict__ f1, const float* __restrict__ f2,
    const float* __restrict__ f3,
    const int* __restrict__ eix, int* __restrict__ cursor,
    unsigned short* __restrict__ Rc, float* __restrict__ fsum,
    int* __restrict__ elist)
{
    int tid = blockIdx.x * 256 + threadIdx.x;   // E*8 threads
    int e = tid >> 3, sub = tid & 7;
    if (e >= N_EDGES) return;
    float a = f1[e], b = f2[e], c = f3[e];
    int k0 = sub * 4;
    float4 r1 = *reinterpret_cast<const float4*>(R1 + (size_t)e * 32 + k0);
    float4 r2 = *reinterpret_cast<const float4*>(R2 + (size_t)e * 32 + k0);
    float4 r3 = *reinterpret_cast<const float4*>(R3 + (size_t)e * 32 + k0);
    ushort4 o;
    o.x = f2bf(r1.x * a + r2.x * b + r3.x * c);
    o.y = f2bf(r1.y * a + r2.y * b + r3.y * c);
    o.z = f2bf(r1.z * a + r2.z * b + r3.z * c);
    o.w = f2bf(r1.w * a + r2.w * b + r3.w * c);
    *reinterpret_cast<ushort4*>(Rc + (size_t)e * 32 + k0) = o;
    if (sub == 0) {
        fsum[e] = a + b + c;
        int slot = atomicAdd(&cursor[eix[e]], 1);
        elist[slot] = e;
    }
}

// ---------------------------------------------------------------------------
// phi = silu(s@W1 + b1) @ W2 + b2, chunk-minor phi2[n][f][c]. 64x256 tiles.
// ---------------------------------------------------------------------------
__global__ __launch_bounds__(256) void phi_kernel(
    const float* __restrict__ s, const unsigned short* __restrict__ W1T,
    const float* __restrict__ b1, const unsigned short* __restrict__ W2T,
    const float* __restrict__ b2, unsigned short* __restrict__ phi2)
{
    __shared__ unsigned short h_lds[64][136];
    int t = threadIdx.x, lane = t & 63, w = t >> 6;
    int quad = lane >> 4, l16 = lane & 15;
    int m0 = (blockIdx.x >> 2) * 64;
    int colg = blockIdx.x & 3;

    int arow = m0 + w * 16 + l16;
    if (arow > N_NODES - 1) arow = N_NODES - 1;
    bf16x8 afr[4];
    #pragma unroll
    for (int ks = 0; ks < 4; ++ks) {
        const float* sp = s + (size_t)arow * 128 + ks * 32 + quad * 8;
        #pragma unroll
        for (int jj = 0; jj < 8; ++jj) afr[ks][jj] = (__bf16)sp[jj];
    }
    #pragma unroll
    for (int cg = 0; cg < 8; ++cg) {
        int col = cg * 16 + l16;
        f32x4 acc = {0.f, 0.f, 0.f, 0.f};
        #pragma unroll
        for (int ks = 0; ks < 4; ++ks) {
            bf16x8 bf = *reinterpret_cast<const bf16x8*>(W1T + (size_t)col * 128 + ks * 32 + quad * 8);
            acc = __builtin_amdgcn_mfma_f32_16x16x32_bf16(afr[ks], bf, acc, 0, 0, 0);
        }
        float bb = b1[col];
        #pragma unroll
        for (int r = 0; r < 4; ++r) {
            int row = w * 16 + quad * 4 + r;
            float val = acc[r] + bb;
            h_lds[row][col] = f2bf(val / (1.f + __expf(-val)));
        }
    }
    __syncthreads();

    bf16x8 a2[4][4];
    #pragma unroll
    for (int rg = 0; rg < 4; ++rg)
        #pragma unroll
        for (int ks = 0; ks < 4; ++ks)
            a2[rg][ks] = *reinterpret_cast<const bf16x8*>(&h_lds[rg * 16 + l16][ks * 32 + quad * 8]);
    #pragma unroll
    for (int i = 0; i < 4; ++i) {
        int col = colg * 256 + w * 64 + i * 16 + l16;
        f32x4 acc2[4] = {{0,0,0,0},{0,0,0,0},{0,0,0,0},{0,0,0,0}};
        #pragma unroll
        for (int ks = 0; ks < 4; ++ks) {
            bf16x8 bf = *reinterpret_cast<const bf16x8*>(W2T + (size_t)col * 128 + ks * 32 + quad * 8);
            #pragma unroll
            for (int rg = 0; rg < 4; ++rg)
                acc2[rg] = __builtin_amdgcn_mfma_f32_16x16x32_bf16(a2[rg][ks], bf, acc2[rg], 0, 0, 0);
        }
        float bb = b2[col];
        int f = col & 127, cc = col >> 7;
        #pragma unroll
        for (int rg = 0; rg < 4; ++rg)
            #pragma unroll
            for (int r = 0; r < 4; ++r) {
                int row = m0 + rg * 16 + quad * 4 + r;
                if (row < N_NODES)
                    phi2[(size_t)row * 1024 + f * 8 + cc] = f2bf(acc2[rg][r] + bb);
            }
    }
}

// ---------------------------------------------------------------------------
// msg: wave-autonomous, NO barriers. Header staged through a PER-WAVE LDS
// slice using R3's proven srow[16][12] layout ({j,fsum,u1,u2,u3,pad}); each
// lane writes 3 values (eid via proven __shfl(eid0,row)), epilogue reads it
// back R3-style. Intra-wave LDS write->read is in-order (single wave).
// First tile of each node folds in +s/+v (out pre-zeroed).
// ---------------------------------------------------------------------------
__global__ __launch_bounds__(256) void msg_kernel(
    const unsigned short* __restrict__ Rc, const float* __restrict__ fsum,
    const int* __restrict__ eix,
    const unsigned short* __restrict__ phi2, const unsigned short* __restrict__ vbf2,
    const unsigned short* __restrict__ WrT, const float* __restrict__ br,
    const int* __restrict__ elist,
    const int* __restrict__ tile_node, const int* __restrict__ tile_e0,
    const int* __restrict__ tile_cnt, const int* __restrict__ ntiles,
    const float* __restrict__ u1, const float* __restrict__ u2,
    const float* __restrict__ u3,
    const float* __restrict__ s, const float* __restrict__ v,
    float* __restrict__ out0, float* __restrict__ out1)
{
    __shared__ float srow[4][16][12];
    int t = threadIdx.x, lane = t & 63, wid = t >> 6;
    int gw = blockIdx.x * 4 + wid;
    int w = gw & 7;                    // fcol group — fixed per wave
    int tile0 = gw >> 3;
    int tstride = (MSG_BLOCKS * 4) >> 3;
    int quad = lane >> 4, l16 = lane & 15;
    int fcol = w * 16 + l16;
    const int* idx_j = eix + N_EDGES;
    const int nt = *ntiles;
    float* sw = &srow[wid][0][0];

    bf16x8 bfrag[8];
    float brv[8];
    #pragma unroll
    for (int c = 0; c < 8; ++c) {
        int col = c * 128 + fcol;
        bfrag[c] = *reinterpret_cast<const bf16x8*>(WrT + (size_t)col * 32 + quad * 8);
        brv[c] = br[col];
    }

    for (int tile = tile0; tile < nt; tile += tstride) {
        int meta = tile_node[tile];
        int node = meta >> 1, first = meta & 1;
        int e0 = tile_e0[tile], tcnt = tile_cnt[tile];

        // edge ids for rows 0..15 live on lanes 0..15 (PROVEN mechanism)
        int eid0 = 0;
        if (lane < 16 && tcnt > 0)
            eid0 = elist[e0 + (lane < tcnt ? lane : 0)];

        // stage header into this wave's LDS slice: 192 values, 3 per lane
        #pragma unroll
        for (int k = 0; k < 3; ++k) {
            int vid = lane * 3 + k;             // 0..191
            int row = vid / 12, c = vid - row * 12;
            int eid = __shfl(eid0, row);
            float val = 0.f;
            if (row < tcnt) {
                if (c == 0)      val = __int_as_float(idx_j[eid]);
                else if (c == 1) val = fsum[eid];
                else if (c < 5)  val = u1[(size_t)eid * 3 + c - 2];
                else if (c < 8)  val = u2[(size_t)eid * 3 + c - 5];
                else if (c < 11) val = u3[(size_t)eid * 3 + c - 8];
            }
            sw[vid] = val;
        }

        // A-fragment via eid shfl (zero for padded rows)
        int eidA = __shfl(eid0, l16);
        bf16x8 af;
        if (l16 < tcnt) {
            af = *reinterpret_cast<const bf16x8*>(Rc + (size_t)eidA * 32 + quad * 8);
        } else {
            #pragma unroll
            for (int q = 0; q < 8; ++q) af[q] = (__bf16)0.f;
        }

        f32x4 acc[8];
        #pragma unroll
        for (int c = 0; c < 8; ++c) {
            f32x4 z = {0.f, 0.f, 0.f, 0.f};
            acc[c] = __builtin_amdgcn_mfma_f32_16x16x32_bf16(af, bfrag[c], z, 0, 0, 0);
        }

        float ds = 0.f, d0 = 0.f, d1 = 0.f, d2 = 0.f;
        #pragma unroll
        for (int r = 0; r < 4; ++r) {
            int row = quad * 4 + r;
            const float* sr = sw + row * 12;
            int j = __float_as_int(sr[0]);
            float fs = sr[1];
            u16x8 ph = *reinterpret_cast<const u16x8*>(phi2 + ((size_t)j * 128 + fcol) * 8);
            ushort4 vb = *reinterpret_cast<const ushort4*>(vbf2 + ((size_t)j * 128 + fcol) * 4);
            float x[8];
            #pragma unroll
            for (int c = 0; c < 8; ++c)
                x[c] = bf2f(ph[c]) * (acc[c][r] + brv[c] * fs);
            float vjx = bf2f(vb.x), vjy = bf2f(vb.y), vjz = bf2f(vb.z);
            float u1x = sr[2], u1y = sr[3], u1z = sr[4];
            float u2x = sr[5], u2y = sr[6], u2z = sr[7];
            float u3x = sr[8], u3y = sr[9], u3z = sr[10];

            ds += x[0];
            d0 += vjx * x[1] + u1x * x[2] + u2x * x[3] + u3x * x[4]
                + x[5] * (vjy * u1z - vjz * u1y)
                + x[6] * (vjy * u2z - vjz * u2y)
                + x[7] * (vjy * u3z - vjz * u3y);
            d1 += vjy * x[1] + u1y * x[2] + u2y * x[3] + u3y * x[4]
                + x[5] * (vjz * u1x - vjx * u1z)
                + x[6] * (vjz * u2x - vjx * u2z)
                + x[7] * (vjz * u3x - vjx * u3z);
            d2 += vjz * x[1] + u1z * x[2] + u2z * x[3] + u3z * x[4]
                + x[5] * (vjx * u1y - vjy * u1x)
                + x[6] * (vjx * u2y - vjy * u2x)
                + x[7] * (vjx * u3y - vjy * u3x);
        }

        ds += __shfl_xor(ds, 16); ds += __shfl_xor(ds, 32);
        d0 += __shfl_xor(d0, 16); d0 += __shfl_xor(d0, 32);
        d1 += __shfl_xor(d1, 16); d1 += __shfl_xor(d1, 32);
        d2 += __shfl_xor(d2, 16); d2 += __shfl_xor(d2, 32);

        if (quad == 0) {
            size_t sbase = (size_t)node * 128 + fcol;
            size_t vbase = (size_t)node * 384 + fcol;
            if (first) {
                ds += s[sbase];
                d0 += v[vbase];
                d1 += v[vbase + 128];
                d2 += v[vbase + 256];
            }
            atomicAdd(&out0[sbase], ds);
            atomicAdd(&out1[vbase], d0);
            atomicAdd(&out1[vbase + 128], d1);
            atomicAdd(&out1[vbase + 256], d2);
        }
    }
}

// ---------------------------------------------------------------------------
extern "C" void kernel_launch(void* const* d_in, const int* in_sizes, int n_in,
                              void* d_out, int out_size, void* d_ws, size_t ws_size,
                              hipStream_t stream) {
    const float* s  = (const float*)d_in[0];
    const float* v  = (const float*)d_in[1];
    const float* R1 = (const float*)d_in[2];
    const float* R2 = (const float*)d_in[3];
    const float* R3 = (const float*)d_in[4];
    const float* f1 = (const float*)d_in[5];
    const float* f2 = (const float*)d_in[6];
    const float* f3 = (const float*)d_in[7];
    const float* u1 = (const float*)d_in[8];
    const float* u2 = (const float*)d_in[9];
    const float* u3 = (const float*)d_in[10];
    const int*  eix = (const int*)d_in[11];
    const float* W1 = (const float*)d_in[12];
    const float* b1 = (const float*)d_in[13];
    const float* W2 = (const float*)d_in[14];
    const float* b2 = (const float*)d_in[15];
    const float* Wr = (const float*)d_in[16];
    const float* br = (const float*)d_in[17];

    char* ws = (char*)d_ws;
    size_t off = 0;
    auto alloc = [&](size_t bytes) -> void* {
        void* p = ws + off;
        off = (off + bytes + 255) & ~(size_t)255;
        return p;
    };
    int* cnt       = (int*)alloc((size_t)N_NODES * 4);
    int* cursor    = (int*)alloc((size_t)N_NODES * 4);
    int* tile_node = (int*)alloc((size_t)MAXT * 4);
    int* tile_e0   = (int*)alloc((size_t)MAXT * 4);
    int* tile_cnt  = (int*)alloc((size_t)MAXT * 4);
    int* ntiles    = (int*)alloc(4);
    int* elist     = (int*)alloc((size_t)N_EDGES * 4);
    unsigned short* Rc   = (unsigned short*)alloc((size_t)N_EDGES * 32 * 2);
    float* fsum          = (float*)alloc((size_t)N_EDGES * 4);
    unsigned short* vbf2 = (unsigned short*)alloc((size_t)N_NODES * 128 * 4 * 2);
    unsigned short* phi2 = (unsigned short*)alloc((size_t)N_NODES * 1024 * 2);
    unsigned short* W1T  = (unsigned short*)alloc(128 * 128 * 2);
    unsigned short* W2T  = (unsigned short*)alloc(1024 * 128 * 2);
    unsigned short* WrT  = (unsigned short*)alloc(1024 * 32 * 2);
    (void)ws_size; (void)in_sizes; (void)n_in;

    float* out0 = (float*)d_out;
    float* out1 = out0 + (size_t)N_NODES * 128;

    hipMemsetAsync(cnt, 0, (size_t)N_NODES * 4, stream);
    hipMemsetAsync(d_out, 0, (size_t)out_size * 4, stream);
    weights_kernel<<<5000, 256, 0, stream>>>(v, eix, W1, W2, Wr,
                                             vbf2, cnt, W1T, W2T, WrT);
    scan_kernel<<<1, 1024, 0, stream>>>(cnt, cursor, tile_node, tile_e0, tile_cnt, ntiles);
    rc_kernel<<<5000, 256, 0, stream>>>(R1, R2, R3, f1, f2, f3, eix, cursor,
                                        Rc, fsum, elist);
    phi_kernel<<<628, 256, 0, stream>>>(s, W1T, b1, W2T, b2, phi2);
    msg_kernel<<<MSG_BLOCKS, 256, 0, stream>>>(Rc, fsum, eix, phi2, vbf2, WrT, br,
                                               elist, tile_node, tile_e0, tile_cnt,
                                               ntiles, u1, u2, u3, s, v, out0, out1);
}

// Round 7
// 460.763 us; speedup vs baseline: 1.0455x; 1.0455x over previous
//
#include <hip/hip_runtime.h>

#define N_NODES 10000
#define N_EDGES 160000
#define MAXT     22000   // >= sum(max(1,ceil(deg/16))) <= 20000
#define MSG_GRID 5000    // tiles strided by MSG_GRID; ~3 tiles/block

typedef __attribute__((ext_vector_type(8))) __bf16 bf16x8;
typedef __attribute__((ext_vector_type(8))) unsigned short u16x8;
typedef __attribute__((ext_vector_type(4))) float f32x4;

static __device__ __forceinline__ unsigned short f2bf(float x) {
    union { float f; unsigned u; } un;
    un.f = x;
    unsigned r = un.u + 0x7fffu + ((un.u >> 16) & 1u);  // RNE
    return (unsigned short)(r >> 16);
}

static __device__ __forceinline__ float bf2f(unsigned short h) {
    union { unsigned u; float f; } un;
    un.u = ((unsigned)h) << 16;
    return un.f;
}

// ---------------------------------------------------------------------------
// weights: W->bf16 transposes, vbf2 pack, degree histogram. 1.28M threads.
// ---------------------------------------------------------------------------
__global__ __launch_bounds__(256) void weights_kernel(
    const float* __restrict__ v, const int* __restrict__ eix,
    const float* __restrict__ W1, const float* __restrict__ W2,
    const float* __restrict__ Wr,
    unsigned short* __restrict__ vbf2, int* __restrict__ cnt,
    unsigned short* __restrict__ W1T, unsigned short* __restrict__ W2T,
    unsigned short* __restrict__ WrT)
{
    int tid = blockIdx.x * 256 + threadIdx.x;
    if (tid < N_NODES * 128) {
        int n = tid >> 7, f = tid & 127;
        ushort4 q;
        q.x = f2bf(v[(size_t)n * 384 + f]);
        q.y = f2bf(v[(size_t)n * 384 + 128 + f]);
        q.z = f2bf(v[(size_t)n * 384 + 256 + f]);
        q.w = 0;
        *reinterpret_cast<ushort4*>(vbf2 + (size_t)tid * 4) = q;
    }
    if (tid < 131072) {                          // W2T [1024][128]
        int n = tid >> 7, k = tid & 127;
        W2T[tid] = f2bf(W2[k * 1024 + n]);
    }
    if (tid < 16384) {                           // W1T [128][128]
        int n = tid >> 7, k = tid & 127;
        W1T[tid] = f2bf(W1[k * 128 + n]);
    }
    if (tid < 32768) {                           // WrT [1024][32]
        int n = tid >> 5, k = tid & 31;
        WrT[tid] = f2bf(Wr[k * 1024 + n]);
    }
    if (tid < N_EDGES) atomicAdd(&cnt[eix[tid]], 1);
}

// ---------------------------------------------------------------------------
// Single-pass dual scan + tile emission (2 barriers). Out-of-range slots
// contribute 0 tiles; deg-0 in-range nodes get 1 empty first-tile.
// ---------------------------------------------------------------------------
#define NPT 10
__global__ __launch_bounds__(1024) void scan_kernel(
    const int* __restrict__ cnt, int* __restrict__ cursor,
    int* __restrict__ tile_node, int* __restrict__ tile_e0,
    int* __restrict__ tile_cnt, int* __restrict__ ntiles)
{
    __shared__ int ws0[16], ws1[16];
    int t = threadIdx.x, lane = t & 63, wid = t >> 6;
    int n0 = t * NPT;
    int deg[NPT], tc[NPT];
    int D = 0, T = 0;
    #pragma unroll
    for (int i = 0; i < NPT; ++i) {
        int idx = n0 + i;
        int d = (idx < N_NODES) ? cnt[idx] : 0;
        deg[i] = d;
        tc[i] = (idx < N_NODES) ? (d ? ((d + 15) >> 4) : 1) : 0;
        D += d; T += tc[i];
    }
    int x0 = D, x1 = T;
    #pragma unroll
    for (int o = 1; o < 64; o <<= 1) {
        int y0 = __shfl_up(x0, o), y1 = __shfl_up(x1, o);
        if (lane >= o) { x0 += y0; x1 += y1; }
    }
    if (lane == 63) { ws0[wid] = x0; ws1[wid] = x1; }
    __syncthreads();
    if (wid == 0) {
        int w0 = (lane < 16) ? ws0[lane] : 0;
        int w1 = (lane < 16) ? ws1[lane] : 0;
        #pragma unroll
        for (int o = 1; o < 16; o <<= 1) {
            int y0 = __shfl_up(w0, o), y1 = __shfl_up(w1, o);
            if (lane >= o) { w0 += y0; w1 += y1; }
        }
        if (lane < 16) { ws0[lane] = w0; ws1[lane] = w1; }
    }
    __syncthreads();
    int e0 = (wid ? ws0[wid - 1] : 0) + x0 - D;
    int t0 = (wid ? ws1[wid - 1] : 0) + x1 - T;
    #pragma unroll
    for (int i = 0; i < NPT; ++i) {
        int idx = n0 + i;
        if (idx < N_NODES) {
            cursor[idx] = e0;
            for (int k = 0; k < tc[i]; ++k) {
                tile_node[t0 + k] = (idx << 1) | (k == 0);
                tile_e0[t0 + k]   = e0 + k * 16;
                int rem = deg[i] - k * 16;
                tile_cnt[t0 + k]  = rem < 0 ? 0 : (rem < 16 ? rem : 16);
            }
            e0 += deg[i]; t0 += tc[i];
        }
    }
    if (t == 1023) *ntiles = t0;
}

// ---------------------------------------------------------------------------
// FUSED rc|phi kernel. Blocks 0..627: phi GEMM (MFMA-bound). Blocks
// 628..5627: rc (BW-bound). Independent work overlapping on the machine.
// ---------------------------------------------------------------------------
#define PHI_BLOCKS 628
__global__ __launch_bounds__(256) void rcphi_kernel(
    // rc args
    const float* __restrict__ R1, const float* __restrict__ R2,
    const float* __restrict__ R3,
    const float* __restrict__ f1, const float* __restrict__ f2,
    const float* __restrict__ f3,
    const int* __restrict__ eix, int* __restrict__ cursor,
    unsigned short* __restrict__ Rc, float* __restrict__ fsum,
    int* __restrict__ elist,
    // phi args
    const float* __restrict__ s, const unsigned short* __restrict__ W1T,
    const float* __restrict__ b1, const unsigned short* __restrict__ W2T,
    const float* __restrict__ b2, unsigned short* __restrict__ phi2)
{
    __shared__ unsigned short h_lds[64][136];
    if (blockIdx.x >= PHI_BLOCKS) {
        // ---------------- rc part ----------------
        int tid = (blockIdx.x - PHI_BLOCKS) * 256 + threadIdx.x;   // E*8 threads
        int e = tid >> 3, sub = tid & 7;
        if (e >= N_EDGES) return;
        float a = f1[e], b = f2[e], c = f3[e];
        int k0 = sub * 4;
        float4 r1 = *reinterpret_cast<const float4*>(R1 + (size_t)e * 32 + k0);
        float4 r2 = *reinterpret_cast<const float4*>(R2 + (size_t)e * 32 + k0);
        float4 r3 = *reinterpret_cast<const float4*>(R3 + (size_t)e * 32 + k0);
        ushort4 o;
        o.x = f2bf(r1.x * a + r2.x * b + r3.x * c);
        o.y = f2bf(r1.y * a + r2.y * b + r3.y * c);
        o.z = f2bf(r1.z * a + r2.z * b + r3.z * c);
        o.w = f2bf(r1.w * a + r2.w * b + r3.w * c);
        *reinterpret_cast<ushort4*>(Rc + (size_t)e * 32 + k0) = o;
        if (sub == 0) {
            fsum[e] = a + b + c;
            int slot = atomicAdd(&cursor[eix[e]], 1);
            elist[slot] = e;
        }
        return;
    }
    // ---------------- phi part ----------------
    int t = threadIdx.x, lane = t & 63, w = t >> 6;
    int quad = lane >> 4, l16 = lane & 15;
    int m0 = (blockIdx.x >> 2) * 64;
    int colg = blockIdx.x & 3;

    int arow = m0 + w * 16 + l16;
    if (arow > N_NODES - 1) arow = N_NODES - 1;
    bf16x8 afr[4];
    #pragma unroll
    for (int ks = 0; ks < 4; ++ks) {
        const float* sp = s + (size_t)arow * 128 + ks * 32 + quad * 8;
        #pragma unroll
        for (int jj = 0; jj < 8; ++jj) afr[ks][jj] = (__bf16)sp[jj];
    }
    #pragma unroll
    for (int cg = 0; cg < 8; ++cg) {
        int col = cg * 16 + l16;
        f32x4 acc = {0.f, 0.f, 0.f, 0.f};
        #pragma unroll
        for (int ks = 0; ks < 4; ++ks) {
            bf16x8 bf = *reinterpret_cast<const bf16x8*>(W1T + (size_t)col * 128 + ks * 32 + quad * 8);
            acc = __builtin_amdgcn_mfma_f32_16x16x32_bf16(afr[ks], bf, acc, 0, 0, 0);
        }
        float bb = b1[col];
        #pragma unroll
        for (int r = 0; r < 4; ++r) {
            int row = w * 16 + quad * 4 + r;
            float val = acc[r] + bb;
            h_lds[row][col] = f2bf(val / (1.f + __expf(-val)));
        }
    }
    __syncthreads();

    bf16x8 a2[4][4];
    #pragma unroll
    for (int rg = 0; rg < 4; ++rg)
        #pragma unroll
        for (int ks = 0; ks < 4; ++ks)
            a2[rg][ks] = *reinterpret_cast<const bf16x8*>(&h_lds[rg * 16 + l16][ks * 32 + quad * 8]);
    #pragma unroll
    for (int i = 0; i < 4; ++i) {
        int col = colg * 256 + w * 64 + i * 16 + l16;
        f32x4 acc2[4] = {{0,0,0,0},{0,0,0,0},{0,0,0,0},{0,0,0,0}};
        #pragma unroll
        for (int ks = 0; ks < 4; ++ks) {
            bf16x8 bf = *reinterpret_cast<const bf16x8*>(W2T + (size_t)col * 128 + ks * 32 + quad * 8);
            #pragma unroll
            for (int rg = 0; rg < 4; ++rg)
                acc2[rg] = __builtin_amdgcn_mfma_f32_16x16x32_bf16(a2[rg][ks], bf, acc2[rg], 0, 0, 0);
        }
        float bb = b2[col];
        int f = col & 127, cc = col >> 7;
        #pragma unroll
        for (int rg = 0; rg < 4; ++rg)
            #pragma unroll
            for (int r = 0; r < 4; ++r) {
                int row = m0 + rg * 16 + quad * 4 + r;
                if (row < N_NODES)
                    phi2[(size_t)row * 1024 + f * 8 + cc] = f2bf(acc2[rg][r] + bb);
            }
    }
}

// ---------------------------------------------------------------------------
// msg: R3's proven block-tile structure (512 thr, 8 waves, block-shared LDS
// header, branchless epilogue) + cross-tile SW pipelining: next tile's meta,
// header values and A-fragment eids prefetched into registers during the
// current tile's MFMA/epilogue; ONE barrier per tile. First tile of each
// node folds in +s/+v (out pre-zeroed).
// ---------------------------------------------------------------------------
__global__ __launch_bounds__(512) void msg_kernel(
    const unsigned short* __restrict__ Rc, const float* __restrict__ fsum,
    const int* __restrict__ eix,
    const unsigned short* __restrict__ phi2, const unsigned short* __restrict__ vbf2,
    const unsigned short* __restrict__ WrT, const float* __restrict__ br,
    const int* __restrict__ elist,
    const int* __restrict__ tile_node, const int* __restrict__ tile_e0,
    const int* __restrict__ tile_cnt, const int* __restrict__ ntiles,
    const float* __restrict__ u1, const float* __restrict__ u2,
    const float* __restrict__ u3,
    const float* __restrict__ s, const float* __restrict__ v,
    float* __restrict__ out0, float* __restrict__ out1)
{
    __shared__ float srow[2][16][12];  // [j, fsum, u1xyz, u2xyz, u3xyz, pad]
    int t = threadIdx.x, lane = t & 63, w = t >> 6;
    int quad = lane >> 4, l16 = lane & 15;
    int fcol = w * 16 + l16;
    const int* idx_j = eix + N_EDGES;
    const int nt = *ntiles;

    bf16x8 bfrag[8];
    float brv[8];
    #pragma unroll
    for (int c = 0; c < 8; ++c) {
        int col = c * 128 + fcol;
        bfrag[c] = *reinterpret_cast<const bf16x8*>(WrT + (size_t)col * 32 + quad * 8);
        brv[c] = br[col];
    }

    int hrow = t / 12, hc = t - hrow * 12;   // header mapping, valid t<192
    bool is_hdr = (t < 192);

    // ---- prologue: load tile0 state into registers ----
    int tile = blockIdx.x;
    int meta = 0, e0 = 0, tcnt = 0, eidA = 0;
    float hval = 0.f;
    if (tile < nt) {
        meta = tile_node[tile]; e0 = tile_e0[tile]; tcnt = tile_cnt[tile];
        if (tcnt > 0) eidA = elist[e0 + (l16 < tcnt ? l16 : 0)];
        if (is_hdr && hrow < tcnt) {
            int eid = elist[e0 + hrow];
            hval = (hc == 0) ? __int_as_float(idx_j[eid])
                 : (hc == 1) ? fsum[eid]
                 : (hc < 5)  ? u1[(size_t)eid * 3 + hc - 2]
                 : (hc < 8)  ? u2[(size_t)eid * 3 + hc - 5]
                 : (hc < 11) ? u3[(size_t)eid * 3 + hc - 8] : 0.f;
        }
    }

    int p = 0;
    while (tile < nt) {
        // 1. stage current header into LDS (padded rows stay 0)
        if (is_hdr) srow[p][hrow][hc] = hval;

        // 2. A-fragment for current tile
        bf16x8 af;
        if (l16 < tcnt) {
            af = *reinterpret_cast<const bf16x8*>(Rc + (size_t)eidA * 32 + quad * 8);
        } else {
            #pragma unroll
            for (int q = 0; q < 8; ++q) af[q] = (__bf16)0.f;
        }

        // 3. prefetch next tile's state into registers (overlaps MFMA+epilogue)
        int tile2 = tile + MSG_GRID;
        int meta2 = 0, e02 = 0, tc2 = 0, eidA2 = 0;
        float hval2 = 0.f;
        if (tile2 < nt) {
            meta2 = tile_node[tile2]; e02 = tile_e0[tile2]; tc2 = tile_cnt[tile2];
            if (tc2 > 0) eidA2 = elist[e02 + (l16 < tc2 ? l16 : 0)];
            if (is_hdr && hrow < tc2) {
                int eid = elist[e02 + hrow];
                hval2 = (hc == 0) ? __int_as_float(idx_j[eid])
                      : (hc == 1) ? fsum[eid]
                      : (hc < 5)  ? u1[(size_t)eid * 3 + hc - 2]
                      : (hc < 8)  ? u2[(size_t)eid * 3 + hc - 5]
                      : (hc < 11) ? u3[(size_t)eid * 3 + hc - 8] : 0.f;
            }
        }

        // 4. MFMA: radial filter for 16 edges x this wave's 16 fcols x 8 chunks
        f32x4 acc[8];
        #pragma unroll
        for (int c = 0; c < 8; ++c) {
            f32x4 z = {0.f, 0.f, 0.f, 0.f};
            acc[c] = __builtin_amdgcn_mfma_f32_16x16x32_bf16(af, bfrag[c], z, 0, 0, 0);
        }

        // 5. one barrier: header visible to all waves
        __syncthreads();

        // 6. epilogue (reads srow[p], gathers phi2/vbf2, geometry, reduce)
        float ds = 0.f, d0 = 0.f, d1 = 0.f, d2 = 0.f;
        #pragma unroll
        for (int r = 0; r < 4; ++r) {
            int row = quad * 4 + r;
            const float* sr = &srow[p][row][0];
            int j = __float_as_int(sr[0]);
            float fs = sr[1];
            u16x8 ph = *reinterpret_cast<const u16x8*>(phi2 + ((size_t)j * 128 + fcol) * 8);
            ushort4 vb = *reinterpret_cast<const ushort4*>(vbf2 + ((size_t)j * 128 + fcol) * 4);
            float x[8];
            #pragma unroll
            for (int c = 0; c < 8; ++c)
                x[c] = bf2f(ph[c]) * (acc[c][r] + brv[c] * fs);
            float vjx = bf2f(vb.x), vjy = bf2f(vb.y), vjz = bf2f(vb.z);
            float u1x = sr[2], u1y = sr[3], u1z = sr[4];
            float u2x = sr[5], u2y = sr[6], u2z = sr[7];
            float u3x = sr[8], u3y = sr[9], u3z = sr[10];

            ds += x[0];
            d0 += vjx * x[1] + u1x * x[2] + u2x * x[3] + u3x * x[4]
                + x[5] * (vjy * u1z - vjz * u1y)
                + x[6] * (vjy * u2z - vjz * u2y)
                + x[7] * (vjy * u3z - vjz * u3y);
            d1 += vjy * x[1] + u1y * x[2] + u2y * x[3] + u3y * x[4]
                + x[5] * (vjz * u1x - vjx * u1z)
                + x[6] * (vjz * u2x - vjx * u2z)
                + x[7] * (vjz * u3x - vjx * u3z);
            d2 += vjz * x[1] + u1z * x[2] + u2z * x[3] + u3z * x[4]
                + x[5] * (vjx * u1y - vjy * u1x)
                + x[6] * (vjx * u2y - vjy * u2x)
                + x[7] * (vjx * u3y - vjy * u3x);
        }

        ds += __shfl_xor(ds, 16); ds += __shfl_xor(ds, 32);
        d0 += __shfl_xor(d0, 16); d0 += __shfl_xor(d0, 32);
        d1 += __shfl_xor(d1, 16); d1 += __shfl_xor(d1, 32);
        d2 += __shfl_xor(d2, 16); d2 += __shfl_xor(d2, 32);

        if (quad == 0) {
            int node = meta >> 1, first = meta & 1;
            size_t sbase = (size_t)node * 128 + fcol;
            size_t vbase = (size_t)node * 384 + fcol;
            if (first) {
                ds += s[sbase];
                d0 += v[vbase];
                d1 += v[vbase + 128];
                d2 += v[vbase + 256];
            }
            atomicAdd(&out0[sbase], ds);
            atomicAdd(&out1[vbase], d0);
            atomicAdd(&out1[vbase + 128], d1);
            atomicAdd(&out1[vbase + 256], d2);
        }

        // 7. rotate prefetched state
        meta = meta2; e0 = e02; tcnt = tc2; eidA = eidA2; hval = hval2;
        tile = tile2; p ^= 1;
    }
}

// ---------------------------------------------------------------------------
extern "C" void kernel_launch(void* const* d_in, const int* in_sizes, int n_in,
                              void* d_out, int out_size, void* d_ws, size_t ws_size,
                              hipStream_t stream) {
    const float* s  = (const float*)d_in[0];
    const float* v  = (const float*)d_in[1];
    const float* R1 = (const float*)d_in[2];
    const float* R2 = (const float*)d_in[3];
    const float* R3 = (const float*)d_in[4];
    const float* f1 = (const float*)d_in[5];
    const float* f2 = (const float*)d_in[6];
    const float* f3 = (const float*)d_in[7];
    const float* u1 = (const float*)d_in[8];
    const float* u2 = (const float*)d_in[9];
    const float* u3 = (const float*)d_in[10];
    const int*  eix = (const int*)d_in[11];
    const float* W1 = (const float*)d_in[12];
    const float* b1 = (const float*)d_in[13];
    const float* W2 = (const float*)d_in[14];
    const float* b2 = (const float*)d_in[15];
    const float* Wr = (const float*)d_in[16];
    const float* br = (const float*)d_in[17];

    char* ws = (char*)d_ws;
    size_t off = 0;
    auto alloc = [&](size_t bytes) -> void* {
        void* p = ws + off;
        off = (off + bytes + 255) & ~(size_t)255;
        return p;
    };
    int* cnt       = (int*)alloc((size_t)N_NODES * 4);
    int* cursor    = (int*)alloc((size_t)N_NODES * 4);
    int* tile_node = (int*)alloc((size_t)MAXT * 4);
    int* tile_e0   = (int*)alloc((size_t)MAXT * 4);
    int* tile_cnt  = (int*)alloc((size_t)MAXT * 4);
    int* ntiles    = (int*)alloc(4);
    int* elist     = (int*)alloc((size_t)N_EDGES * 4);
    unsigned short* Rc   = (unsigned short*)alloc((size_t)N_EDGES * 32 * 2);
    float* fsum          = (float*)alloc((size_t)N_EDGES * 4);
    unsigned short* vbf2 = (unsigned short*)alloc((size_t)N_NODES * 128 * 4 * 2);
    unsigned short* phi2 = (unsigned short*)alloc((size_t)N_NODES * 1024 * 2);
    unsigned short* W1T  = (unsigned short*)alloc(128 * 128 * 2);
    unsigned short* W2T  = (unsigned short*)alloc(1024 * 128 * 2);
    unsigned short* WrT  = (unsigned short*)alloc(1024 * 32 * 2);
    (void)ws_size; (void)in_sizes; (void)n_in;

    float* out0 = (float*)d_out;
    float* out1 = out0 + (size_t)N_NODES * 128;

    hipMemsetAsync(cnt, 0, (size_t)N_NODES * 4, stream);
    hipMemsetAsync(d_out, 0, (size_t)out_size * 4, stream);
    weights_kernel<<<5000, 256, 0, stream>>>(v, eix, W1, W2, Wr,
                                             vbf2, cnt, W1T, W2T, WrT);
    scan_kernel<<<1, 1024, 0, stream>>>(cnt, cursor, tile_node, tile_e0, tile_cnt, ntiles);
    rcphi_kernel<<<PHI_BLOCKS + 5000, 256, 0, stream>>>(
        R1, R2, R3, f1, f2, f3, eix, cursor, Rc, fsum, elist,
        s, W1T, b1, W2T, b2, phi2);
    msg_kernel<<<MSG_GRID, 512, 0, stream>>>(Rc, fsum, eix, phi2, vbf2, WrT, br,
                                             elist, tile_node, tile_e0, tile_cnt,
                                             ntiles, u1, u2, u3, s, v, out0, out1);
}

// Round 8
// 441.708 us; speedup vs baseline: 1.0906x; 1.0431x over previous
//
#include <hip/hip_runtime.h>

#define N_NODES 10000
#define N_EDGES 160000
#define MAXT     30000   // half-tiles: sum(max(1,ceil(d/8))) <= N + E/8 = 30000
#define MSG_GRID 4096    // blocks; each strides over full tiles (pairs of half-tiles)

typedef __attribute__((ext_vector_type(8))) __bf16 bf16x8;
typedef __attribute__((ext_vector_type(8))) unsigned short u16x8;
typedef __attribute__((ext_vector_type(4))) float f32x4;

static __device__ __forceinline__ unsigned short f2bf(float x) {
    union { float f; unsigned u; } un;
    un.f = x;
    unsigned r = un.u + 0x7fffu + ((un.u >> 16) & 1u);  // RNE
    return (unsigned short)(r >> 16);
}

static __device__ __forceinline__ float bf2f(unsigned short h) {
    union { unsigned u; float f; } un;
    un.u = ((unsigned)h) << 16;
    return un.f;
}

// ---------------------------------------------------------------------------
// weights: W->bf16 transposes, vbf2 pack, degree histogram. 1.28M threads.
// ---------------------------------------------------------------------------
__global__ __launch_bounds__(256) void weights_kernel(
    const float* __restrict__ v, const int* __restrict__ eix,
    const float* __restrict__ W1, const float* __restrict__ W2,
    const float* __restrict__ Wr,
    unsigned short* __restrict__ vbf2, int* __restrict__ cnt,
    unsigned short* __restrict__ W1T, unsigned short* __restrict__ W2T,
    unsigned short* __restrict__ WrT)
{
    int tid = blockIdx.x * 256 + threadIdx.x;
    if (tid < N_NODES * 128) {
        int n = tid >> 7, f = tid & 127;
        ushort4 q;
        q.x = f2bf(v[(size_t)n * 384 + f]);
        q.y = f2bf(v[(size_t)n * 384 + 128 + f]);
        q.z = f2bf(v[(size_t)n * 384 + 256 + f]);
        q.w = 0;
        *reinterpret_cast<ushort4*>(vbf2 + (size_t)tid * 4) = q;
    }
    if (tid < 131072) {                          // W2T [1024][128]
        int n = tid >> 7, k = tid & 127;
        W2T[tid] = f2bf(W2[k * 1024 + n]);
    }
    if (tid < 16384) {                           // W1T [128][128]
        int n = tid >> 7, k = tid & 127;
        W1T[tid] = f2bf(W1[k * 128 + n]);
    }
    if (tid < 32768) {                           // WrT [1024][32]
        int n = tid >> 5, k = tid & 31;
        WrT[tid] = f2bf(Wr[k * 1024 + n]);
    }
    if (tid < N_EDGES) atomicAdd(&cnt[eix[tid]], 1);
}

// ---------------------------------------------------------------------------
// Single-pass dual scan + HALF-TILE emission (8-edge granularity; 2 barriers).
// Out-of-range slots contribute 0; deg-0 in-range nodes get 1 empty half-tile
// (so s/v pass through via the first-tile fold in msg).
// ---------------------------------------------------------------------------
#define NPT 10
__global__ __launch_bounds__(1024) void scan_kernel(
    const int* __restrict__ cnt, int* __restrict__ cursor,
    int* __restrict__ tile_node, int* __restrict__ tile_e0,
    int* __restrict__ tile_cnt, int* __restrict__ ntiles)
{
    __shared__ int ws0[16], ws1[16];
    int t = threadIdx.x, lane = t & 63, wid = t >> 6;
    int n0 = t * NPT;
    int deg[NPT], tc[NPT];
    int D = 0, T = 0;
    #pragma unroll
    for (int i = 0; i < NPT; ++i) {
        int idx = n0 + i;
        int d = (idx < N_NODES) ? cnt[idx] : 0;
        deg[i] = d;
        tc[i] = (idx < N_NODES) ? (d ? ((d + 7) >> 3) : 1) : 0;
        D += d; T += tc[i];
    }
    int x0 = D, x1 = T;
    #pragma unroll
    for (int o = 1; o < 64; o <<= 1) {
        int y0 = __shfl_up(x0, o), y1 = __shfl_up(x1, o);
        if (lane >= o) { x0 += y0; x1 += y1; }
    }
    if (lane == 63) { ws0[wid] = x0; ws1[wid] = x1; }
    __syncthreads();
    if (wid == 0) {
        int w0 = (lane < 16) ? ws0[lane] : 0;
        int w1 = (lane < 16) ? ws1[lane] : 0;
        #pragma unroll
        for (int o = 1; o < 16; o <<= 1) {
            int y0 = __shfl_up(w0, o), y1 = __shfl_up(w1, o);
            if (lane >= o) { w0 += y0; w1 += y1; }
        }
        if (lane < 16) { ws0[lane] = w0; ws1[lane] = w1; }
    }
    __syncthreads();
    int e0 = (wid ? ws0[wid - 1] : 0) + x0 - D;
    int t0 = (wid ? ws1[wid - 1] : 0) + x1 - T;
    #pragma unroll
    for (int i = 0; i < NPT; ++i) {
        int idx = n0 + i;
        if (idx < N_NODES) {
            cursor[idx] = e0;
            for (int k = 0; k < tc[i]; ++k) {
                tile_node[t0 + k] = (idx << 1) | (k == 0);
                tile_e0[t0 + k]   = e0 + k * 8;
                int rem = deg[i] - k * 8;
                tile_cnt[t0 + k]  = rem < 0 ? 0 : (rem < 8 ? rem : 8);
            }
            e0 += deg[i]; t0 += tc[i];
        }
    }
    if (t == 1023) *ntiles = t0;
}

// ---------------------------------------------------------------------------
// FUSED rc|phi kernel. Blocks 0..627: phi GEMM (MFMA-bound). Blocks
// 628..5627: rc (BW-bound). Independent work overlapping on the machine.
// ---------------------------------------------------------------------------
#define PHI_BLOCKS 628
__global__ __launch_bounds__(256) void rcphi_kernel(
    const float* __restrict__ R1, const float* __restrict__ R2,
    const float* __restrict__ R3,
    const float* __restrict__ f1, const float* __restrict__ f2,
    const float* __restrict__ f3,
    const int* __restrict__ eix, int* __restrict__ cursor,
    unsigned short* __restrict__ Rc, float* __restrict__ fsum,
    int* __restrict__ elist,
    const float* __restrict__ s, const unsigned short* __restrict__ W1T,
    const float* __restrict__ b1, const unsigned short* __restrict__ W2T,
    const float* __restrict__ b2, unsigned short* __restrict__ phi2)
{
    __shared__ unsigned short h_lds[64][136];
    if (blockIdx.x >= PHI_BLOCKS) {
        // ---------------- rc part ----------------
        int tid = (blockIdx.x - PHI_BLOCKS) * 256 + threadIdx.x;   // E*8 threads
        int e = tid >> 3, sub = tid & 7;
        if (e >= N_EDGES) return;
        float a = f1[e], b = f2[e], c = f3[e];
        int k0 = sub * 4;
        float4 r1 = *reinterpret_cast<const float4*>(R1 + (size_t)e * 32 + k0);
        float4 r2 = *reinterpret_cast<const float4*>(R2 + (size_t)e * 32 + k0);
        float4 r3 = *reinterpret_cast<const float4*>(R3 + (size_t)e * 32 + k0);
        ushort4 o;
        o.x = f2bf(r1.x * a + r2.x * b + r3.x * c);
        o.y = f2bf(r1.y * a + r2.y * b + r3.y * c);
        o.z = f2bf(r1.z * a + r2.z * b + r3.z * c);
        o.w = f2bf(r1.w * a + r2.w * b + r3.w * c);
        *reinterpret_cast<ushort4*>(Rc + (size_t)e * 32 + k0) = o;
        if (sub == 0) {
            fsum[e] = a + b + c;
            int slot = atomicAdd(&cursor[eix[e]], 1);
            elist[slot] = e;
        }
        return;
    }
    // ---------------- phi part ----------------
    int t = threadIdx.x, lane = t & 63, w = t >> 6;
    int quad = lane >> 4, l16 = lane & 15;
    int m0 = (blockIdx.x >> 2) * 64;
    int colg = blockIdx.x & 3;

    int arow = m0 + w * 16 + l16;
    if (arow > N_NODES - 1) arow = N_NODES - 1;
    bf16x8 afr[4];
    #pragma unroll
    for (int ks = 0; ks < 4; ++ks) {
        const float* sp = s + (size_t)arow * 128 + ks * 32 + quad * 8;
        #pragma unroll
        for (int jj = 0; jj < 8; ++jj) afr[ks][jj] = (__bf16)sp[jj];
    }
    #pragma unroll
    for (int cg = 0; cg < 8; ++cg) {
        int col = cg * 16 + l16;
        f32x4 acc = {0.f, 0.f, 0.f, 0.f};
        #pragma unroll
        for (int ks = 0; ks < 4; ++ks) {
            bf16x8 bf = *reinterpret_cast<const bf16x8*>(W1T + (size_t)col * 128 + ks * 32 + quad * 8);
            acc = __builtin_amdgcn_mfma_f32_16x16x32_bf16(afr[ks], bf, acc, 0, 0, 0);
        }
        float bb = b1[col];
        #pragma unroll
        for (int r = 0; r < 4; ++r) {
            int row = w * 16 + quad * 4 + r;
            float val = acc[r] + bb;
            h_lds[row][col] = f2bf(val / (1.f + __expf(-val)));
        }
    }
    __syncthreads();

    bf16x8 a2[4][4];
    #pragma unroll
    for (int rg = 0; rg < 4; ++rg)
        #pragma unroll
        for (int ks = 0; ks < 4; ++ks)
            a2[rg][ks] = *reinterpret_cast<const bf16x8*>(&h_lds[rg * 16 + l16][ks * 32 + quad * 8]);
    #pragma unroll
    for (int i = 0; i < 4; ++i) {
        int col = colg * 256 + w * 64 + i * 16 + l16;
        f32x4 acc2[4] = {{0,0,0,0},{0,0,0,0},{0,0,0,0},{0,0,0,0}};
        #pragma unroll
        for (int ks = 0; ks < 4; ++ks) {
            bf16x8 bf = *reinterpret_cast<const bf16x8*>(W2T + (size_t)col * 128 + ks * 32 + quad * 8);
            #pragma unroll
            for (int rg = 0; rg < 4; ++rg)
                acc2[rg] = __builtin_amdgcn_mfma_f32_16x16x32_bf16(a2[rg][ks], bf, acc2[rg], 0, 0, 0);
        }
        float bb = b2[col];
        int f = col & 127, cc = col >> 7;
        #pragma unroll
        for (int rg = 0; rg < 4; ++rg)
            #pragma unroll
            for (int r = 0; r < 4; ++r) {
                int row = m0 + rg * 16 + quad * 4 + r;
                if (row < N_NODES)
                    phi2[(size_t)row * 1024 + f * 8 + cc] = f2bf(acc2[rg][r] + bb);
            }
    }
}

// ---------------------------------------------------------------------------
// msg: R3's PROVEN structure (512 thr, 8 waves, block-shared dbuf LDS header,
// one barrier/tile, branchless epilogue) with HALF-TILE packing: one MFMA
// tile = two 8-edge half-tiles (rows 0-7 node A, rows 8-15 node B) -> ~37%
// less padding work. Reduction stops at shfl_xor(16); quad0 writes A,
// quad2 writes B. First half-tile of each node folds in +s/+v (out zeroed).
// ---------------------------------------------------------------------------
__global__ __launch_bounds__(512) void msg_kernel(
    const unsigned short* __restrict__ Rc, const float* __restrict__ fsum,
    const int* __restrict__ eix,
    const unsigned short* __restrict__ phi2, const unsigned short* __restrict__ vbf2,
    const unsigned short* __restrict__ WrT, const float* __restrict__ br,
    const int* __restrict__ elist,
    const int* __restrict__ tile_node, const int* __restrict__ tile_e0,
    const int* __restrict__ tile_cnt, const int* __restrict__ ntiles,
    const float* __restrict__ u1, const float* __restrict__ u2,
    const float* __restrict__ u3,
    const float* __restrict__ s, const float* __restrict__ v,
    float* __restrict__ out0, float* __restrict__ out1)
{
    __shared__ float srow[2][16][12];  // [j, fsum, u1xyz, u2xyz, u3xyz, pad]
    int t = threadIdx.x, lane = t & 63, w = t >> 6;
    int quad = lane >> 4, l16 = lane & 15;
    int fcol = w * 16 + l16;
    const int* idx_j = eix + N_EDGES;
    const int nht = *ntiles;
    const int nft = (nht + 1) >> 1;

    bf16x8 bfrag[8];
    float brv[8];
    #pragma unroll
    for (int c = 0; c < 8; ++c) {
        int col = c * 128 + fcol;
        bfrag[c] = *reinterpret_cast<const bf16x8*>(WrT + (size_t)col * 32 + quad * 8);
        brv[c] = br[col];
    }

    int hrow = t / 12, hc = t - hrow * 12;   // header mapping, valid t<192
    bool is_hdr = (t < 192);

    int p = 0;
    for (int ft = blockIdx.x; ft < nft; ft += MSG_GRID) {
        int htA = 2 * ft, htB = 2 * ft + 1;
        int metaA = tile_node[htA], e0A = tile_e0[htA], cntA = tile_cnt[htA];
        int metaB = 0, e0B = 0, cntB = 0;
        if (htB < nht) {
            metaB = tile_node[htB]; e0B = tile_e0[htB]; cntB = tile_cnt[htB];
        }

        // header: 192 threads, one scattered load each (invalid rows -> 0)
        if (is_hdr) {
            int erow = (hrow < 8) ? hrow : hrow - 8;
            int ecnt = (hrow < 8) ? cntA : cntB;
            int ebase = (hrow < 8) ? e0A : e0B;
            float val = 0.f;
            if (erow < ecnt) {
                int eid = elist[ebase + erow];
                val = (hc == 0) ? __int_as_float(idx_j[eid])
                    : (hc == 1) ? fsum[eid]
                    : (hc < 5)  ? u1[(size_t)eid * 3 + hc - 2]
                    : (hc < 8)  ? u2[(size_t)eid * 3 + hc - 5]
                    : (hc < 11) ? u3[(size_t)eid * 3 + hc - 8] : 0.f;
            }
            srow[p][hrow][hc] = val;
        }

        // A-fragment: rows 0-7 from half A, rows 8-15 from half B
        int arow = (l16 < 8) ? l16 : l16 - 8;
        int acnt = (l16 < 8) ? cntA : cntB;
        int abase = (l16 < 8) ? e0A : e0B;
        bf16x8 af;
        if (arow < acnt) {
            int eidA = elist[abase + arow];
            af = *reinterpret_cast<const bf16x8*>(Rc + (size_t)eidA * 32 + quad * 8);
        } else {
            #pragma unroll
            for (int q = 0; q < 8; ++q) af[q] = (__bf16)0.f;
        }

        f32x4 acc[8];
        #pragma unroll
        for (int c = 0; c < 8; ++c) {
            f32x4 z = {0.f, 0.f, 0.f, 0.f};
            acc[c] = __builtin_amdgcn_mfma_f32_16x16x32_bf16(af, bfrag[c], z, 0, 0, 0);
        }

        __syncthreads();   // header visible; epilogue reads srow[p]

        float ds = 0.f, d0 = 0.f, d1 = 0.f, d2 = 0.f;
        #pragma unroll
        for (int r = 0; r < 4; ++r) {
            int row = quad * 4 + r;
            const float* sr = &srow[p][row][0];
            int j = __float_as_int(sr[0]);
            float fs = sr[1];
            u16x8 ph = *reinterpret_cast<const u16x8*>(phi2 + ((size_t)j * 128 + fcol) * 8);
            ushort4 vb = *reinterpret_cast<const ushort4*>(vbf2 + ((size_t)j * 128 + fcol) * 4);
            float x[8];
            #pragma unroll
            for (int c = 0; c < 8; ++c)
                x[c] = bf2f(ph[c]) * (acc[c][r] + brv[c] * fs);
            float vjx = bf2f(vb.x), vjy = bf2f(vb.y), vjz = bf2f(vb.z);
            float u1x = sr[2], u1y = sr[3], u1z = sr[4];
            float u2x = sr[5], u2y = sr[6], u2z = sr[7];
            float u3x = sr[8], u3y = sr[9], u3z = sr[10];

            ds += x[0];
            d0 += vjx * x[1] + u1x * x[2] + u2x * x[3] + u3x * x[4]
                + x[5] * (vjy * u1z - vjz * u1y)
                + x[6] * (vjy * u2z - vjz * u2y)
                + x[7] * (vjy * u3z - vjz * u3y);
            d1 += vjy * x[1] + u1y * x[2] + u2y * x[3] + u3y * x[4]
                + x[5] * (vjz * u1x - vjx * u1z)
                + x[6] * (vjz * u2x - vjx * u2z)
                + x[7] * (vjz * u3x - vjx * u3z);
            d2 += vjz * x[1] + u1z * x[2] + u2z * x[3] + u3z * x[4]
                + x[5] * (vjx * u1y - vjy * u1x)
                + x[6] * (vjx * u2y - vjy * u2x)
                + x[7] * (vjx * u3y - vjy * u3x);
        }

        // merge quad pairs only: quads 0+1 = node A, quads 2+3 = node B
        ds += __shfl_xor(ds, 16);
        d0 += __shfl_xor(d0, 16);
        d1 += __shfl_xor(d1, 16);
        d2 += __shfl_xor(d2, 16);

        if ((quad & 1) == 0) {
            int meta = (quad == 0) ? metaA : metaB;
            int node = meta >> 1, first = meta & 1;
            size_t sbase = (size_t)node * 128 + fcol;
            size_t vbase = (size_t)node * 384 + fcol;
            if (first) {
                ds += s[sbase];
                d0 += v[vbase];
                d1 += v[vbase + 128];
                d2 += v[vbase + 256];
            }
            atomicAdd(&out0[sbase], ds);
            atomicAdd(&out1[vbase], d0);
            atomicAdd(&out1[vbase + 128], d1);
            atomicAdd(&out1[vbase + 256], d2);
        }

        p ^= 1;
    }
}

// ---------------------------------------------------------------------------
extern "C" void kernel_launch(void* const* d_in, const int* in_sizes, int n_in,
                              void* d_out, int out_size, void* d_ws, size_t ws_size,
                              hipStream_t stream) {
    const float* s  = (const float*)d_in[0];
    const float* v  = (const float*)d_in[1];
    const float* R1 = (const float*)d_in[2];
    const float* R2 = (const float*)d_in[3];
    const float* R3 = (const float*)d_in[4];
    const float* f1 = (const float*)d_in[5];
    const float* f2 = (const float*)d_in[6];
    const float* f3 = (const float*)d_in[7];
    const float* u1 = (const float*)d_in[8];
    const float* u2 = (const float*)d_in[9];
    const float* u3 = (const float*)d_in[10];
    const int*  eix = (const int*)d_in[11];
    const float* W1 = (const float*)d_in[12];
    const float* b1 = (const float*)d_in[13];
    const float* W2 = (const float*)d_in[14];
    const float* b2 = (const float*)d_in[15];
    const float* Wr = (const float*)d_in[16];
    const float* br = (const float*)d_in[17];

    char* ws = (char*)d_ws;
    size_t off = 0;
    auto alloc = [&](size_t bytes) -> void* {
        void* p = ws + off;
        off = (off + bytes + 255) & ~(size_t)255;
        return p;
    };
    int* cnt       = (int*)alloc((size_t)N_NODES * 4);
    int* cursor    = (int*)alloc((size_t)N_NODES * 4);
    int* tile_node = (int*)alloc((size_t)MAXT * 4);
    int* tile_e0   = (int*)alloc((size_t)MAXT * 4);
    int* tile_cnt  = (int*)alloc((size_t)MAXT * 4);
    int* ntiles    = (int*)alloc(4);
    int* elist     = (int*)alloc((size_t)N_EDGES * 4);
    unsigned short* Rc   = (unsigned short*)alloc((size_t)N_EDGES * 32 * 2);
    float* fsum          = (float*)alloc((size_t)N_EDGES * 4);
    unsigned short* vbf2 = (unsigned short*)alloc((size_t)N_NODES * 128 * 4 * 2);
    unsigned short* phi2 = (unsigned short*)alloc((size_t)N_NODES * 1024 * 2);
    unsigned short* W1T  = (unsigned short*)alloc(128 * 128 * 2);
    unsigned short* W2T  = (unsigned short*)alloc(1024 * 128 * 2);
    unsigned short* WrT  = (unsigned short*)alloc(1024 * 32 * 2);
    (void)ws_size; (void)in_sizes; (void)n_in;

    float* out0 = (float*)d_out;
    float* out1 = out0 + (size_t)N_NODES * 128;

    hipMemsetAsync(cnt, 0, (size_t)N_NODES * 4, stream);
    hipMemsetAsync(d_out, 0, (size_t)out_size * 4, stream);
    weights_kernel<<<5000, 256, 0, stream>>>(v, eix, W1, W2, Wr,
                                             vbf2, cnt, W1T, W2T, WrT);
    scan_kernel<<<1, 1024, 0, stream>>>(cnt, cursor, tile_node, tile_e0, tile_cnt, ntiles);
    rcphi_kernel<<<PHI_BLOCKS + 5000, 256, 0, stream>>>(
        R1, R2, R3, f1, f2, f3, eix, cursor, Rc, fsum, elist,
        s, W1T, b1, W2T, b2, phi2);
    msg_kernel<<<MSG_GRID, 512, 0, stream>>>(Rc, fsum, eix, phi2, vbf2, WrT, br,
                                             elist, tile_node, tile_e0, tile_cnt,
                                             ntiles, u1, u2, u3, s, v, out0, out1);
}